// Round 10
// baseline (640.103 us; speedup 1.0000x reference)
//
#include <hip/hip_runtime.h>

#define ZN 131072          // B*H*W rows
#define DD 64              // embedding dim
#define KK 1024            // codebook entries
#define BSTRIDE 262144     // 64*64*64 (per-batch stride in z)
#define DSTRIDE 4096       // per-d stride in z (H*W)
#define ZQ_ELEMS 8388608   // 32*64*64*64

// ---- workspace layout ----
// [0,8)               double   loss accumulator
// [8,12)              unsigned flagged-row count
// [16,4112)           float    csq32[1024]   (numpy-emulated fp32)
// [4112,528400)       int      worklist[131072]
// [528400,790544)     float    cbT[64][1024] (transposed codebook, for refine)
// [790544,921616)     ushort   cb_hi[1024][64] (bf16 high split)
// [921616,1052688)    ushort   cb_lo[1024][64] (bf16 low split)
#define WS_CSQ_OFF   16
#define WS_WORK_OFF  4112
#define WS_CBT_OFF   528400
#define WS_CBH_OFF   790544
#define WS_CBL_OFF   921616

typedef short s8v __attribute__((ext_vector_type(8)));   // 8 bf16 (4 VGPRs)
typedef float f4v __attribute__((ext_vector_type(4)));   // MFMA C/D

__device__ __forceinline__ unsigned short bf16_rne(float f) {
    unsigned u = __float_as_uint(f);
    return (unsigned short)((u + 0x7fffu + ((u >> 16) & 1u)) >> 16);
}

// numpy-emulated fp32 sum of a[i]^2 over 64 elems (pairwise, 8 accumulators).
__device__ __forceinline__ float np_sumsq64(const float* a) {
    float r0 = __fmul_rn(a[0], a[0]), r1 = __fmul_rn(a[1], a[1]);
    float r2 = __fmul_rn(a[2], a[2]), r3 = __fmul_rn(a[3], a[3]);
    float r4 = __fmul_rn(a[4], a[4]), r5 = __fmul_rn(a[5], a[5]);
    float r6 = __fmul_rn(a[6], a[6]), r7 = __fmul_rn(a[7], a[7]);
#pragma unroll
    for (int i = 8; i < 64; i += 8) {
        r0 = __fadd_rn(r0, __fmul_rn(a[i + 0], a[i + 0]));
        r1 = __fadd_rn(r1, __fmul_rn(a[i + 1], a[i + 1]));
        r2 = __fadd_rn(r2, __fmul_rn(a[i + 2], a[i + 2]));
        r3 = __fadd_rn(r3, __fmul_rn(a[i + 3], a[i + 3]));
        r4 = __fadd_rn(r4, __fmul_rn(a[i + 4], a[i + 4]));
        r5 = __fadd_rn(r5, __fmul_rn(a[i + 5], a[i + 5]));
        r6 = __fadd_rn(r6, __fmul_rn(a[i + 6], a[i + 6]));
        r7 = __fadd_rn(r7, __fmul_rn(a[i + 7], a[i + 7]));
    }
    return __fadd_rn(__fadd_rn(__fadd_rn(r0, r1), __fadd_rn(r2, r3)),
                     __fadd_rn(__fadd_rn(r4, r5), __fadd_rn(r6, r7)));
}

// -------- prep: cbT, csq32, bf16 hi/lo split of codebook --------
__global__ __launch_bounds__(256) void vq_prep(const float* __restrict__ cb,
                                               float* __restrict__ cbT,
                                               float* __restrict__ csq,
                                               unsigned short* __restrict__ cbh,
                                               unsigned short* __restrict__ cbl) {
    int i = blockIdx.x * 256 + threadIdx.x;  // 0..65535
    int d = i >> 10, k = i & 1023;
    cbT[i] = cb[k * DD + d];
    float v = cb[i];  // flat i = k*64 + d
    unsigned short h = bf16_rne(v);
    cbh[i] = h;
    cbl[i] = bf16_rne(v - __uint_as_float((unsigned)h << 16));
    if (i < KK) csq[i] = np_sumsq64(cb + i * DD);
}

// -------- MFMA prefilter argmin --------
// Wave = 32 z-rows (2 row-tiles of 16) vs all 1024 codes in 16-code N-tiles.
// Split-bf16: dot = hi*hi + hi*lo + lo*hi (err ~6e-6 << 2e-4 flag margin).
// A-frag: A[m=lane&15][k=quad*8+j]; B-frag symmetric (n=lane&15);
// C/D: col=lane&15 (code), row=quad*4+reg (z-row). B-frags shared by both
// row-tiles -> codebook traffic halved vs 16 rows/wave.
__global__ __attribute__((amdgpu_waves_per_eu(2))) __launch_bounds__(256)
void vq_argmin(const float* __restrict__ z,
               const unsigned short* __restrict__ cbh,
               const unsigned short* __restrict__ cbl,
               const float* __restrict__ csq,
               float* __restrict__ idxf_out,
               unsigned* __restrict__ count,
               int* __restrict__ worklist) {
    int lane = threadIdx.x & 63;
    int wv = threadIdx.x >> 6;
    int col = lane & 15;
    int quad = lane >> 4;
    int base0 = (blockIdx.x * 4 + wv) * 32;  // 32 rows per wave

    // A fragments (z rows in bf16 hi/lo), built once per wave
    s8v ah[2][2], al[2][2];  // [rowtile][kstep]
#pragma unroll
    for (int rt = 0; rt < 2; ++rt) {
        int n = base0 + rt * 16 + col;  // base0 mult of 32 -> same batch b
        int b = n >> 12, p = n & 4095;
        const float* zp = z + (size_t)b * BSTRIDE + p;
#pragma unroll
        for (int ks = 0; ks < 2; ++ks) {
#pragma unroll
            for (int j = 0; j < 8; ++j) {
                int d = ks * 32 + quad * 8 + j;
                float v = zp[(size_t)d * DSTRIDE];
                unsigned short h = bf16_rne(v);
                ah[rt][ks][j] = (short)h;
                al[rt][ks][j] = (short)bf16_rne(v - __uint_as_float((unsigned)h << 16));
            }
        }
    }

    float min1[2][4], min2[2][4];
    int best[2][4];
#pragma unroll
    for (int rt = 0; rt < 2; ++rt)
#pragma unroll
        for (int r = 0; r < 4; ++r) {
            min1[rt][r] = 3.4e38f;
            min2[rt][r] = 3.4e38f;
            best[rt][r] = 0;
        }

    for (int t = 0; t < 64; ++t) {  // uniform N-tile loop
        const unsigned short* bh = cbh + (t * 16 + col) * DD + quad * 8;
        const unsigned short* bl = cbl + (t * 16 + col) * DD + quad * 8;
        s8v bh0 = *(const s8v*)(bh);
        s8v bh1 = *(const s8v*)(bh + 32);
        s8v bl0 = *(const s8v*)(bl);
        s8v bl1 = *(const s8v*)(bl + 32);
        float cs = csq[t * 16 + col];
        int k = t * 16 + col;
#pragma unroll
        for (int rt = 0; rt < 2; ++rt) {
            f4v acc = {0.f, 0.f, 0.f, 0.f};
            acc = __builtin_amdgcn_mfma_f32_16x16x32_bf16(ah[rt][0], bh0, acc, 0, 0, 0);
            acc = __builtin_amdgcn_mfma_f32_16x16x32_bf16(ah[rt][1], bh1, acc, 0, 0, 0);
            acc = __builtin_amdgcn_mfma_f32_16x16x32_bf16(ah[rt][0], bl0, acc, 0, 0, 0);
            acc = __builtin_amdgcn_mfma_f32_16x16x32_bf16(ah[rt][1], bl1, acc, 0, 0, 0);
            acc = __builtin_amdgcn_mfma_f32_16x16x32_bf16(al[rt][0], bh0, acc, 0, 0, 0);
            acc = __builtin_amdgcn_mfma_f32_16x16x32_bf16(al[rt][1], bh1, acc, 0, 0, 0);
#pragma unroll
            for (int r = 0; r < 4; ++r) {
                float dist = fmaf(-2.f, acc[r], cs);
                bool lt = dist < min1[rt][r];  // strict: lowest k on ties (t asc)
                float o = min1[rt][r];
                min1[rt][r] = lt ? dist : min1[rt][r];
                min2[rt][r] = lt ? o : fminf(min2[rt][r], dist);
                best[rt][r] = lt ? k : best[rt][r];
            }
        }
    }

    // merge the 16 cols (lanes within a quad); packed u64 -> ties pick lowest k
#pragma unroll
    for (int rt = 0; rt < 2; ++rt)
#pragma unroll
        for (int r = 0; r < 4; ++r) {
            unsigned ub = __float_as_uint(min1[rt][r]);
            ub = (ub & 0x80000000u) ? ~ub : (ub | 0x80000000u);  // order-preserving
            unsigned long long pk = ((unsigned long long)ub << 32) | (unsigned)best[rt][r];
            float m2 = min2[rt][r];
#pragma unroll
            for (int off = 1; off < 16; off <<= 1) {
                unsigned long long o = (unsigned long long)__shfl_xor((long long)pk, off, 64);
                float o2 = __shfl_xor(m2, off, 64);
                unsigned long long l = pk > o ? pk : o;  // loser
                unsigned lu = (unsigned)(l >> 32);
                lu = (lu & 0x80000000u) ? (lu & 0x7fffffffu) : ~lu;  // unpack min1
                m2 = fminf(fminf(m2, o2), __uint_as_float(lu));
                pk = pk < o ? pk : o;
            }
            if (col == 0) {  // lanes 0,16,32,48 write rows quad*4+r
                int n = base0 + rt * 16 + quad * 4 + r;
                idxf_out[n] = (float)(unsigned)(pk & 0xFFFFFFFFull);
                unsigned wu = (unsigned)(pk >> 32);
                wu = (wu & 0x80000000u) ? (wu & 0x7fffffffu) : ~wu;
                float d1 = __uint_as_float(wu);
                // flag margin covers ref fp32 noise (~1.6e-5) + mfma err (~6e-6)
                if (m2 - d1 < 2e-4f) worklist[atomicAdd(count, 1u)] = n;
            }
        }
}

// -------- reference-fp32-emulated argmin for flagged rows: WAVE per row ----
// (R9-proven structure; zsq now recomputed locally from the LDS zrow with
// the exact numpy pairwise order — bit-identical to the old global pass.)
__global__ __launch_bounds__(256) void vq_refine(const float* __restrict__ z,
                                                 const float* __restrict__ cbT,
                                                 const float* __restrict__ csq,
                                                 const unsigned* __restrict__ count,
                                                 const int* __restrict__ worklist,
                                                 float* __restrict__ idxf_out) {
    __shared__ float zrow[4][DD];
    unsigned cnt = *count;
    int tl = threadIdx.x & 63;
    int wv = threadIdx.x >> 6;
    unsigned wave = blockIdx.x * 4 + wv;
    unsigned nwaves = gridDim.x * 4;
    for (unsigned r = wave; r < cnt; r += nwaves) {
        int n = worklist[r];
        int b = n >> 12, p = n & 4095;
        zrow[wv][tl] = z[(size_t)b * BSTRIDE + (size_t)tl * DSTRIDE + p];
        // same-wave LDS dep: compiler inserts lgkmcnt wait

        float zsq = np_sumsq64(&zrow[wv][0]);  // broadcast reads, wave-uniform

        double acc[16];
#pragma unroll
        for (int j = 0; j < 16; ++j) acc[j] = 0.0;
#pragma unroll 2
        for (int d = 0; d < DD; ++d) {
            double zd = (double)zrow[wv][d];  // LDS broadcast
            const float* crow = cbT + d * KK + tl;
#pragma unroll
            for (int j = 0; j < 16; ++j)  // lane-coalesced 256B loads
                acc[j] = fma(zd, (double)crow[64 * j], acc[j]);
        }

        unsigned long long pk = ~0ull;
#pragma unroll
        for (int j = 0; j < 16; ++j) {
            int k = 64 * j + tl;
            float twoC = (float)(2.0 * acc[j]);  // ~sgemm output, corr. rounded
            float dist = __fsub_rn(__fadd_rn(zsq, csq[k]), twoC);  // ref fp32 ops
            unsigned ub = __float_as_uint(dist);
            ub = (ub & 0x80000000u) ? ~ub : (ub | 0x80000000u);
            unsigned long long cand = ((unsigned long long)ub << 32) | (unsigned)k;
            pk = cand < pk ? cand : pk;  // min dist, then lowest k
        }
#pragma unroll
        for (int off = 32; off; off >>= 1) {
            unsigned long long o = (unsigned long long)__shfl_xor((long long)pk, off, 64);
            pk = pk < o ? pk : o;
        }
        if (tl == 0) idxf_out[n] = (float)(unsigned)(pk & 0xFFFFFFFFull);
    }
}

// -------- gather z_q + fused loss partial reduction (R7/R9-proven) --------
__global__ __launch_bounds__(256) void vq_gather_loss(const float* __restrict__ z,
                                                      const float* __restrict__ cb,
                                                      const float* __restrict__ idxf,
                                                      float* __restrict__ zq_out,
                                                      double* __restrict__ acc) {
    int n = blockIdx.x * 256 + threadIdx.x;
    int b = n >> 12, p = n & 4095;
    const float* zp = z + (size_t)b * BSTRIDE + p;
    float* qp = zq_out + (size_t)b * BSTRIDE + p;
    int k = (int)idxf[n];
    const float* c = cb + k * DD;

    float s = 0.f;
#pragma unroll
    for (int d = 0; d < DD; ++d) {
        float q = c[d];
        float diff = q - zp[(size_t)d * DSTRIDE];
        s = fmaf(diff, diff, s);
        qp[(size_t)d * DSTRIDE] = q;  // z_q_st == z_q numerically
    }

#pragma unroll
    for (int off = 32; off; off >>= 1) s += __shfl_down(s, off, 64);
    __shared__ float partial[4];
    if ((threadIdx.x & 63) == 0) partial[threadIdx.x >> 6] = s;
    __syncthreads();
    if (threadIdx.x == 0) {
        float t = (partial[0] + partial[1]) + (partial[2] + partial[3]);
        atomicAdd(acc, (double)t);
    }
}

__global__ void vq_finalize(const double* __restrict__ acc, float* __restrict__ loss_out) {
    *loss_out = (float)(1.25 * (*acc) / (double)ZQ_ELEMS);
}

extern "C" void kernel_launch(void* const* d_in, const int* in_sizes, int n_in,
                              void* d_out, int out_size, void* d_ws, size_t ws_size,
                              hipStream_t stream) {
    const float* z = (const float*)d_in[0];
    const float* cb = (const float*)d_in[1];
    float* out = (float*)d_out;

    float* zq_out = out;                   // [0, 8388608)
    float* loss_out = out + ZQ_ELEMS;      // [8388608]
    float* idxf_out = out + ZQ_ELEMS + 1;  // [8388609, +131072)

    char* ws = (char*)d_ws;
    double* acc = (double*)ws;
    unsigned* count = (unsigned*)(ws + 8);
    float* csq = (float*)(ws + WS_CSQ_OFF);
    int* worklist = (int*)(ws + WS_WORK_OFF);
    float* cbT = (float*)(ws + WS_CBT_OFF);
    unsigned short* cbh = (unsigned short*)(ws + WS_CBH_OFF);
    unsigned short* cbl = (unsigned short*)(ws + WS_CBL_OFF);

    hipMemsetAsync(d_ws, 0, 16, stream);  // acc=0, count=0

    vq_prep<<<KK * DD / 256, 256, 0, stream>>>(cb, cbT, csq, cbh, cbl);
    vq_argmin<<<ZN / 128, 256, 0, stream>>>(z, cbh, cbl, csq, idxf_out, count, worklist);
    vq_refine<<<1024, 256, 0, stream>>>(z, cbT, csq, count, worklist, idxf_out);
    vq_gather_loss<<<ZN / 256, 256, 0, stream>>>(z, cb, idxf_out, zq_out, acc);
    vq_finalize<<<1, 1, 0, stream>>>(acc, loss_out);
}